// Round 6
// baseline (128.917 us; speedup 1.0000x reference)
//
#include <hip/hip_runtime.h>

#define NPTS (8 * 65536)

// CALIBRATION PROBE R6 — measure warm-launch marginal cost.
// Identical kernel to R5 (same outputs; kernel is idempotent: pure overwrite,
// no read-modify-write). kernel_launch enqueues it FOUR times back-to-back:
//   dur = fill(42) + k1(cold) + 3 * k_warm
// Launches 2-4 run with warm L3/K$/ramped clock -> separates the ~25us fixed
// per-launch cost (cold-state) from intrinsic work, and puts warm dispatches
// into rocprof with their own VALUBusy/FETCH_SIZE rows.

__global__ __launch_bounds__(256, 8) void cubeflow_fused(
    const float* __restrict__ input,
    const float* __restrict__ latent,
    const float* __restrict__ W1,
    const float* __restrict__ b1,
    const float* __restrict__ W2,
    const float* __restrict__ b2,
    float* __restrict__ out)
{
    const int t     = threadIdx.x;
    const int base  = blockIdx.x * 1024;          // 512 blocks
    const int batch = base >> 16;                 // 64 blocks per batch
    const float theta = latent[batch] * 10.0f;    // uniform per block (SGPR)

    // ---- load 4 points (lane-major, coalesced) ----
    float x0[4], x1[4], x2[4];
    int p[4];
#pragma unroll
    for (int k = 0; k < 4; ++k) {
        p[k] = base + t + 256 * k;
        const float* ip = input + 3 * p[k];
        x0[k] = ip[0];
        x1[k] = ip[1];
        x2[k] = ip[2];
    }

    float* __restrict__ out_eval  = out;             // NPTS
    float* __restrict__ out_con   = out + NPTS;      // NPTS*4
    float* __restrict__ out_probs = out + 5 * NPTS;  // NPTS*2

    // ---- eval + con (fp32, exact) ----
    {
        const float cth = cosf(theta);
        const float sth = sinf(theta);
#pragma unroll
        for (int k = 0; k < 4; ++k) {
            const float d0 = x0[k] - theta;
            const float d1 = x1[k];
            const float d2 = x2[k];
            const float f1 = fmaf(1.4f * d0, d0, fmaf(1.4f * d1, d1, 0.2f * d2 * d2)) - 0.5f;
            const float c2x = fmaf(cth, d0,  sth * d1);
            const float c2y = fmaf(cth, d1, -sth * d0);
            const float c2z = d2 + 0.4f;
            const float f2 = fmaf(3.8f * c2x, c2x, fmaf(0.6f * c2y, c2y, 3.8f * c2z * c2z)) - 0.5f;
            const float c3x = fmaf(cth, d0, -sth * d1);
            const float c3y = fmaf(sth, d0,  cth * d1);
            const float c3z = d2 - 0.6f;
            const float f3 = fmaf(0.35f * c3x, c3x, fmaf(2.8f * c3y, c3y, 2.8f * c3z * c3z)) - 0.5f;
            out_eval[p[k]] = fminf(f1, fminf(f2, f3));
            *reinterpret_cast<float4*>(out_con + 4 * p[k]) =
                make_float4(x0[k], x1[k], x2[k], theta);
        }
    }

    // ---- MLP: 128 hidden units x 4 points, weights via s_load ----
    float a0[4], a1[4];
    {
        const float B0 = b2[0];
        const float B1 = b2[1];
#pragma unroll
        for (int k = 0; k < 4; ++k) { a0[k] = B0; a1[k] = B1; }
    }

#pragma unroll 8
    for (int h = 0; h < 128; ++h) {
        const float w0   = W1[4 * h + 0];     // uniform -> s_load (merged)
        const float w1   = W1[4 * h + 1];
        const float w2   = W1[4 * h + 2];
        const float bias = fmaf(theta, W1[4 * h + 3], b1[h]);
        const float w20  = W2[h];
        const float w21  = W2[128 + h];
#pragma unroll
        for (int k = 0; k < 4; ++k) {
            float hv = fmaf(x0[k], w0, fmaf(x1[k], w1, fmaf(x2[k], w2, bias)));
            hv = fmaxf(hv, 0.0f);
            a0[k] = fmaf(hv, w20, a0[k]);
            a1[k] = fmaf(hv, w21, a1[k]);
        }
    }

#pragma unroll
    for (int k = 0; k < 4; ++k) {
        *reinterpret_cast<float2*>(out_probs + 2 * p[k]) = make_float2(a0[k], a1[k]);
    }
}

extern "C" void kernel_launch(void* const* d_in, const int* in_sizes, int n_in,
                              void* d_out, int out_size, void* d_ws, size_t ws_size,
                              hipStream_t stream) {
    const float* input  = (const float*)d_in[0];
    const float* latent = (const float*)d_in[1];
    const float* W1     = (const float*)d_in[2];
    const float* b1     = (const float*)d_in[3];
    const float* W2     = (const float*)d_in[4];
    const float* b2     = (const float*)d_in[5];
    float* out = (float*)d_out;

    const int nblocks = NPTS / 1024;   // 512
    // PROBE: 4 identical launches (idempotent kernel, outputs unchanged).
    for (int rep = 0; rep < 4; ++rep) {
        hipLaunchKernelGGL(cubeflow_fused, dim3(nblocks), dim3(256), 0, stream,
                           input, latent, W1, b1, W2, b2, out);
    }
}